// Round 8
// baseline (78.025 us; speedup 1.0000x reference)
//
#include <hip/hip_runtime.h>
#include <hip/hip_bf16.h>

// Conv2dKan, fused MFMA kernel. b=16, cin=cout=64, H=W=32, K=3, PAD=1, BASIS=8.
// out[b,o,pix] = bias[o] + sum_{i,k,s8} Wt[i,k,o,s]*act(x[b,i,pix+off(k)])[s]
//   Wt[...,0]=w, Wt[...,s]=w*c[s] (s=1..7) bf16, layout [i][kpos][o][s]
//   act(x) = [silu(x), T1..T7(tanh x)] bf16; act(pad) = act(0) = [0,0,-1,0,1,0,-1,0]
//   bias[o] = sum_{i,k} w*c[...,0]  (T0==1)
// R24 == R23 RESUBMIT (round-7 bench died to container infra, no kernel verdict).
// R23 = R22 dataflow (32x32x16 MFMA, read-once Wt = 147MB aggregate, af-LDS
//   halved) restructured for SMALL BARRIER DOMAINS + 2 independent blocks/CU:
//   R22 (74.9) sat 2.5x above every pipe floor and was insensitive to traffic
//   halvings -> residual = barrier-convoy stalls of one 16-wave lockstep block.
//   - xlds DROPPED but coalescing KEPT (R19's failure inverted): act cells are
//     ch-major (cell=(kqc*2+chl)*136+pos) -> consecutive lanes read consecutive
//     pos of ONE channel -> 2-3 lines per wave-load, straight from L2/L3.
//     LDS = 2 act bufs = 69632 B -> 2 blocks/CU (two independent 8-wave
//     barrier domains per CU; act/MFMA/epilogue overlap across blocks).
//   - grid 512 = (16b x 2oh, 16rp), block 512 = 8 waves (kq8). Wave = 64pix
//     (2 rows) x 32o (oh tile) x 8ch, acc0/acc1 = rows. Wt read once/block.
//   - T14: next chunk's 5 x-values prefetched before the barrier (chunk adds
//     +2048 floats to a chunk-invariant address), land under MFMA(c).
//   - setprio(1) around MFMA: with 2 blocks/CU at different phases there is
//     real role diversity (m191-positive regime, not m190-null lockstep).
//   - 32x32 layouts (HW-verified R21/R22): C/D col=lane&31(pix),
//     row=(reg&3)+8*(reg>>2)+4*(lane>>5); A row=lane&31(o), k=(lane>>5)*8+s;
//     B col=lane&31(pix), k=(lane>>5)*8+s.
//   Epilogue: red[kq8][pix64][33] f32 = 67584 B overlays buf0+part of buf1 ->
//   extra barrier after the chunk loop before red writes.
// Hang-audit (pre-resubmit): uniform barriers (predicates inside loops only);
//   dead-cell xoff computed but never dereferenced; red max = 67584B <= 69632B;
//   VGPR est ~70 < 128 cap. No change needed.

#define CIN   64
#define COUT  64
#define HW    32
#define LL    1024
#define NS    8

typedef __attribute__((ext_vector_type(8))) short short8;
typedef __attribute__((ext_vector_type(16))) float f32x16;

// ws layout (bytes):
//   [0)       Wt    : 64*9*64*8 bf16 = 589824 B   ([i][kpos][o][s])
//   [589824)  bias  : 64 f32         = 256 B
//   [590080)  dummy : keep-alive sink for prefetch

__global__ void prep_kernel(const float* __restrict__ w,
                            const float* __restrict__ c,
                            __hip_bfloat16* __restrict__ Wt,
                            float* __restrict__ bias,
                            const float* __restrict__ x,
                            float* __restrict__ dummy) {
    const int bx = blockIdx.x;
    if (bx < 144) {
        // Wt part
        const int tid = bx * 256 + threadIdx.x;   // < 36864 = 64i*9k*64o
        const int i = tid / (9 * COUT);
        const int r = tid - i * 9 * COUT;
        const int k = r / COUT;
        const int o = r - k * COUT;
        const int widx = (i * COUT + o) * 9 + k;
        const float wv = w[widx];
        __hip_bfloat16* dst = Wt + (size_t)tid * NS;   // tid == (i*9+k)*64+o
        dst[0] = __float2bfloat16(wv);
#pragma unroll
        for (int s = 1; s < 8; ++s) dst[s] = __float2bfloat16(wv * c[widx * 8 + s]);
        return;
    }
    if (bx < 208) {
        // bias part: 64 blocks, one o each; 64-lane wave reduce over i.
        const int o = bx - 144;
        const int i = threadIdx.x;
        if (i >= 64) return;
        float v = 0.f;
#pragma unroll
        for (int k = 0; k < 9; ++k) {
            const int idx = (i * COUT + o) * 9 + k;
            v += w[idx] * c[idx * 8];
        }
#pragma unroll
        for (int off = 32; off > 0; off >>= 1) v += __shfl_down(v, off);
        if (i == 0) bias[o] = v;
        return;
    }
    // x-prefetch part: 1024 blocks, each touches one (b,ch) 4KB image -> L3/L2 warm.
    const int idx = bx - 208;          // [0,1024)
    const int r  = idx & 7;
    const int m  = idx >> 3;
    const int b  = r + 8 * (m & 1);
    const int ch = m >> 1;
    const float4 v = ((const float4*)(x + (size_t)(b * CIN + ch) * LL))[threadIdx.x];
    const float acc = v.x + v.y + v.z + v.w;
    if (acc == 1.0e-37f) dummy[threadIdx.x] = acc;   // keep-alive; never taken in practice
}

// grid (32 = 16b x 2oh, 16 row-pairs), block 512 = 8 waves (kq8).
// Wave: 64pix (2 rows) x 32o (oh tile) x 8ch.
__global__ __launch_bounds__(512, 4) void kan_fused_kernel(
        const float* __restrict__ x,
        const __hip_bfloat16* __restrict__ Wt,
        const float* __restrict__ bias,
        float* __restrict__ out) {
    // ushort units:
    //   [0,     17408): act scratch buf0 [kq8][chl2][pos136] x 16B  (34816 B)
    //   [17408, 34816): act scratch buf1
    // epilogue overlay: float red[kq8][pix64][33] = 67584 B (covers buf0 + part
    //   of buf1 -> fenced by the post-loop barrier)
    __shared__ __align__(16) unsigned short Wlds[34816];   // 69632 B -> 2 blocks/CU

    const int tid  = threadIdx.x;     // 0..511
    const int kq   = tid >> 6;        // 0..7: channels [kq*8, kq*8+8)
    const int lane = tid & 63;
    const int l31  = lane & 31;
    const int half = lane >> 5;       // K-step channel half

    const int bx   = blockIdx.x;
    const int b    = bx >> 1;
    const int oh   = bx & 1;          // o-tile: [oh*32, oh*32+32)
    const int row0 = blockIdx.y << 1; // first of the 2 output rows

    const unsigned short* WtU = (const unsigned short*)Wt;

    // ---- act-cell geometry (chunk-invariant). 2176 cells/chunk = 16 slots x
    //      136 pos, ch-major: cell = g*136+pos, g = kqc*2+chl; channel for a
    //      chunk = (g>>1)*8 + chunk*2 + (g&1)  (chunk adds +2048 floats). ----
    int    cellv[5];
    bool   liv[5];
    bool   vld[5];
    size_t xoff[5];
#pragma unroll
    for (int p = 0; p < 5; ++p) {
        const int cell = p * 512 + tid;
        const bool live = (p < 4) || (tid < 128);   // 4*512 + 128 = 2176
        const int g   = cell / 136;
        const int pos = cell - g * 136;
        const int r4  = pos / 34;                   // halo row 0..3
        const int col = pos - r4 * 34;
        const int gy  = row0 - 1 + r4;
        const int gx  = col - 1;
        cellv[p] = cell;
        liv[p]   = live;
        vld[p]   = live && ((unsigned)gy < 32u) && ((unsigned)gx < 32u);
        const int ch0 = (g >> 1) * 8 + (g & 1);     // channel at chunk 0
        xoff[p]  = ((size_t)(b * CIN + ch0) * HW + gy) * HW + gx;
    }

    f32x16 acc0, acc1;                // pixel rows 0 and 1 (same o-tile oh)
#pragma unroll
    for (int r = 0; r < 16; ++r) { acc0[r] = 0.f; acc1[r] = 0.f; }

    // lane-invariant Wt base: i = kq*8 + half (+chunk*2), o = oh*32 + l31
    const size_t wlane = ((size_t)(kq * 8 + half) * 9 * COUT + oh * 32 + l31) * NS;

    float xc[5], xn[5];
#pragma unroll
    for (int p = 0; p < 5; ++p) xc[p] = vld[p] ? x[xoff[p]] : 0.f;   // chunk 0

    for (int chunk = 0; chunk < 4; ++chunk) {
        unsigned short* ubuf = Wlds + (chunk & 1) * 17408;

        // ---- T14: issue next chunk's x loads first (land under this MFMA) ----
        if (chunk < 3) {
#pragma unroll
            for (int p = 0; p < 5; ++p)
                xn[p] = vld[p] ? x[xoff[p] + (size_t)(chunk + 1) * 2 * HW * HW] : 0.f;
        }

        // ---- act: branchless (border x=0 -> exact pad vector), single exp ----
#pragma unroll
        for (int p = 0; p < 5; ++p) {
            if (liv[p]) {
                const float xv  = xc[p];
                const float e   = __expf(xv);                         // one exp
                const float sig = e * __builtin_amdgcn_rcpf(1.f + e);
                const float res = xv * sig;                           // silu
                const float t   = 1.f - 2.f * __builtin_amdgcn_rcpf(__builtin_fmaf(e, e, 1.f)); // tanh
                const float t2  = t + t;
                const float T2 = __builtin_fmaf(t2, t,  -1.f);
                const float T3 = __builtin_fmaf(t2, T2, -t);
                const float T4 = __builtin_fmaf(t2, T3, -T2);
                const float T5 = __builtin_fmaf(t2, T4, -T3);
                const float T6 = __builtin_fmaf(t2, T5, -T4);
                const float T7 = __builtin_fmaf(t2, T6, -T5);
                union { __hip_bfloat162 h2[4]; float4 f4; } U;
                U.h2[0] = __float22bfloat162_rn(make_float2(res, t));
                U.h2[1] = __float22bfloat162_rn(make_float2(T2, T3));
                U.h2[2] = __float22bfloat162_rn(make_float2(T4, T5));
                U.h2[3] = __float22bfloat162_rn(make_float2(T6, T7));
                *(float4*)(ubuf + cellv[p] * 8) = U.f4;
            }
        }
        __syncthreads();   // scratch buf[chunk&1] ready

        // ---- MFMA: af from scratch (contiguous b128), wf from global L2,
        //      read once and feeding both rows; setprio vs other block's act ----
        const unsigned short* afb = ubuf + (kq * 2 + half) * 1088;   // [pos136] x 16B
        const unsigned short* wc  = WtU + wlane + (size_t)chunk * 9216; // i += 2
        __builtin_amdgcn_s_setprio(1);
#pragma unroll
        for (int kpos = 0; kpos < 9; ++kpos) {
            const int posb = (kpos / 3) * 34 + (kpos % 3);
            short8 af0 = *(const short8*)(afb + (posb      + l31) * 8);
            short8 af1 = *(const short8*)(afb + (posb + 34 + l31) * 8);
            short8 wf  = *(const short8*)(wc + kpos * 512);
            acc0 = __builtin_amdgcn_mfma_f32_32x32x16_bf16(wf, af0, acc0, 0, 0, 0);
            acc1 = __builtin_amdgcn_mfma_f32_32x32x16_bf16(wf, af1, acc1, 0, 0, 0);
        }
        __builtin_amdgcn_s_setprio(0);

#pragma unroll
        for (int p = 0; p < 5; ++p) xc[p] = xn[p];
    }

    // ---- epilogue: reduce 8 kq-partials via padded LDS. red overlays buf0 and
    //      part of buf1 -> barrier first so all chunk-3 MFMA reads are done. ----
    __syncthreads();
    float* red = (float*)Wlds;       // red[kq8][pix64][33]
#pragma unroll
    for (int r = 0; r < 16; ++r) {
        const int ol = (r & 3) + 8 * (r >> 2) + 4 * half;   // o within 32-tile
        red[(kq * 64 +      l31) * 33 + ol] = acc0[r];      // row 0, pix 0..31
        red[(kq * 64 + 32 + l31) * 33 + ol] = acc1[r];      // row 1, pix 32..63
    }
    __syncthreads();

#pragma unroll
    for (int rep = 0; rep < 4; ++rep) {
        const int v  = rep * 512 + tid;   // 2048 = 64 pix x 32 o
        const int p  = v & 63;
        const int ol = v >> 6;            // o within this block's 32-tile
        float s = bias[oh * 32 + ol];
#pragma unroll
        for (int kqq = 0; kqq < 8; ++kqq)
            s += red[(kqq * 64 + p) * 33 + ol];
        out[(size_t)(b * COUT + oh * 32 + ol) * LL + (row0 + (p >> 5)) * HW + (p & 31)] = s;
    }
}

extern "C" void kernel_launch(void* const* d_in, const int* in_sizes, int n_in,
                              void* d_out, int out_size, void* d_ws, size_t ws_size,
                              hipStream_t stream) {
    const float* x = (const float*)d_in[0];
    const float* w = (const float*)d_in[1];
    const float* c = (const float*)d_in[2];
    float* out = (float*)d_out;

    char* ws = (char*)d_ws;
    __hip_bfloat16* Wt    = (__hip_bfloat16*)(ws);
    float*          bias  = (float*)(ws + 589824);
    float*          dummy = (float*)(ws + 590080);

    // 144 Wt + 64 bias + 1024 x-prefetch = 1232 blocks, all parallel
    prep_kernel<<<1232, 256, 0, stream>>>(w, c, Wt, bias, x, dummy);
    kan_fused_kernel<<<dim3(32, 16), 512, 0, stream>>>(x, Wt, bias, out);
}